// Round 1
// baseline (10606.894 us; speedup 1.0000x reference)
//
#include <hip/hip_runtime.h>

#define N_USERS  200000
#define N_ITEMS  100000
#define N_TOTAL  300000
#define EMB_DIM  64
#define N_EDGES  4000000
#define N_LAYERS 3

// ---------------- degree histogram: deg[src[e]] += 1 ----------------
__global__ void deg_kernel(const int* __restrict__ src, float* __restrict__ deg) {
    int e = blockIdx.x * blockDim.x + threadIdx.x;
    if (e < N_EDGES) {
        unsafeAtomicAdd(&deg[src[e]], 1.0f);
    }
}

// ---------------- dinv = rsqrt(deg + 1e-8), in place ----------------
__global__ void rsqrt_kernel(float* __restrict__ deg) {
    int i = blockIdx.x * blockDim.x + threadIdx.x;
    if (i < N_TOTAL) deg[i] = rsqrtf(deg[i] + 1e-8f);
}

// ------- h = x = concat(user_w, item_w); out(acc) = x  (float4) -------
__global__ void init_kernel(const float4* __restrict__ user_w,
                            const float4* __restrict__ item_w,
                            float4* __restrict__ h,
                            float4* __restrict__ out) {
    int i = blockIdx.x * blockDim.x + threadIdx.x;   // over N_TOTAL*16 float4s
    const int n = N_TOTAL * (EMB_DIM / 4);
    if (i < n) {
        const int userN = N_USERS * (EMB_DIM / 4);
        float4 v = (i < userN) ? user_w[i] : item_w[i - userN];
        h[i] = v;
        out[i] = v;
    }
}

// ---- scatter SpMM: h_next[src] += dinv[src]*dinv[dst] * h_prev[dst] ----
// 16 threads per edge; each handles 4 dims via float4 gather + 4 atomics.
__global__ void scatter_kernel(const int* __restrict__ src,
                               const int* __restrict__ dst,
                               const float* __restrict__ dinv,
                               const float4* __restrict__ h_prev,
                               float* __restrict__ h_next) {
    int t = blockIdx.x * blockDim.x + threadIdx.x;   // N_EDGES*16 threads
    if (t >= N_EDGES * 16) return;
    int e = t >> 4;
    int q = t & 15;
    int s = src[e];
    int d = dst[e];
    float w = dinv[s] * dinv[d];
    float4 v = h_prev[d * 16 + q];
    float* base = h_next + (size_t)s * EMB_DIM + q * 4;
    unsafeAtomicAdd(base + 0, w * v.x);
    unsafeAtomicAdd(base + 1, w * v.y);
    unsafeAtomicAdd(base + 2, w * v.z);
    unsafeAtomicAdd(base + 3, w * v.w);
}

// ---------------- out = (out + h) * scale  (float4) ----------------
__global__ void add_kernel(float4* __restrict__ out,
                           const float4* __restrict__ h,
                           float scale) {
    int i = blockIdx.x * blockDim.x + threadIdx.x;
    const int n = N_TOTAL * (EMB_DIM / 4);
    if (i < n) {
        float4 o = out[i];
        float4 v = h[i];
        o.x = (o.x + v.x) * scale;
        o.y = (o.y + v.y) * scale;
        o.z = (o.z + v.z) * scale;
        o.w = (o.w + v.w) * scale;
        out[i] = o;
    }
}

extern "C" void kernel_launch(void* const* d_in, const int* in_sizes, int n_in,
                              void* d_out, int out_size, void* d_ws, size_t ws_size,
                              hipStream_t stream) {
    const float* user_w = (const float*)d_in[0];
    const float* item_w = (const float*)d_in[1];
    const int*   src    = (const int*)d_in[2];
    const int*   dst    = (const int*)d_in[3];
    float* out = (float*)d_out;

    // workspace layout
    char* ws = (char*)d_ws;
    float* deg = (float*)ws;                                    // N_TOTAL floats
    size_t off = ((size_t)N_TOTAL * 4 + 511) & ~(size_t)511;    // 1,200,128
    float* h_a = (float*)(ws + off);                            // N_TOTAL*64 floats
    off += (size_t)N_TOTAL * EMB_DIM * 4;                       // +76,800,000
    float* h_b = (float*)(ws + off);                            // N_TOTAL*64 floats
    (void)ws_size; (void)in_sizes; (void)n_in; (void)out_size;

    const int B = 256;

    // 1. degree
    hipMemsetAsync(deg, 0, (size_t)N_TOTAL * 4, stream);
    deg_kernel<<<(N_EDGES + B - 1) / B, B, 0, stream>>>(src, deg);
    // 2. dinv
    rsqrt_kernel<<<(N_TOTAL + B - 1) / B, B, 0, stream>>>(deg);
    // 3. h0 = x, acc = x
    {
        int n = N_TOTAL * (EMB_DIM / 4);
        init_kernel<<<(n + B - 1) / B, B, 0, stream>>>(
            (const float4*)user_w, (const float4*)item_w,
            (float4*)h_a, (float4*)out);
    }
    // 4. three propagation layers
    float* h_prev = h_a;
    float* h_next = h_b;
    for (int l = 0; l < N_LAYERS; ++l) {
        hipMemsetAsync(h_next, 0, (size_t)N_TOTAL * EMB_DIM * 4, stream);
        {
            long long nt = (long long)N_EDGES * 16;
            scatter_kernel<<<(int)((nt + B - 1) / B), B, 0, stream>>>(
                src, dst, deg, (const float4*)h_prev, h_next);
        }
        {
            int n = N_TOTAL * (EMB_DIM / 4);
            float scale = (l == N_LAYERS - 1) ? (1.0f / (N_LAYERS + 1)) : 1.0f;
            add_kernel<<<(n + B - 1) / B, B, 0, stream>>>(
                (float4*)out, (const float4*)h_next, scale);
        }
        float* tmp = h_prev; h_prev = h_next; h_next = tmp;
    }
}

// Round 2
// 1825.906 us; speedup vs baseline: 5.8091x; 5.8091x over previous
//
#include <hip/hip_runtime.h>

#define N_USERS  200000
#define N_ITEMS  100000
#define N_TOTAL  300000
#define EMB_DIM  64
#define N_EDGES  4000000
#define N_LAYERS 3

#define SCAN_CHUNK 1024                      // elements per scan block
#define N_SCAN_BLOCKS ((N_TOTAL + SCAN_CHUNK - 1) / SCAN_CHUNK)   // 293

// ---------------- 1. degree histogram (int): counts[src[e]]++ ----------------
__global__ void hist_kernel(const int* __restrict__ src, int* __restrict__ counts) {
    int e = blockIdx.x * blockDim.x + threadIdx.x;
    if (e < N_EDGES) atomicAdd(&counts[src[e]], 1);
}

// ---------------- 2a. per-block exclusive scan of counts -> offs ----------------
__global__ void scanA_kernel(const int* __restrict__ counts,
                             int* __restrict__ offs,
                             int* __restrict__ blocksums) {
    __shared__ int lds[256];
    int t = threadIdx.x, b = blockIdx.x;
    int base = b * SCAN_CHUNK + t * 4;
    int v[4];
#pragma unroll
    for (int k = 0; k < 4; ++k)
        v[k] = (base + k < N_TOTAL) ? counts[base + k] : 0;
    int s = v[0] + v[1] + v[2] + v[3];
    lds[t] = s;
    __syncthreads();
    // Hillis-Steele inclusive scan over 256 thread-sums
    for (int off = 1; off < 256; off <<= 1) {
        int x = (t >= off) ? lds[t - off] : 0;
        __syncthreads();
        lds[t] += x;
        __syncthreads();
    }
    int inc = lds[t];
    int exc = inc - s;
    if (t == 255) blocksums[b] = inc;
    int run = exc;
#pragma unroll
    for (int k = 0; k < 4; ++k) {
        if (base + k < N_TOTAL) offs[base + k] = run;
        run += v[k];
    }
}

// ---------------- 2b. scan the 293 block sums (single thread) ----------------
__global__ void scanB_kernel(int* __restrict__ blocksums, int* __restrict__ offs) {
    if (threadIdx.x == 0 && blockIdx.x == 0) {
        int run = 0;
        for (int i = 0; i < N_SCAN_BLOCKS; ++i) {
            int t = blocksums[i];
            blocksums[i] = run;
            run += t;
        }
        offs[N_TOTAL] = run;   // == N_EDGES
    }
}

// ------- 2c. add block offsets; cursor = offs  -------
__global__ void scanC_kernel(int* __restrict__ offs,
                             const int* __restrict__ blocksums,
                             int* __restrict__ cursor) {
    int i = blockIdx.x * blockDim.x + threadIdx.x;
    if (i < N_TOTAL) {
        int o = offs[i] + blocksums[i >> 10];
        offs[i] = o;
        cursor[i] = o;
    }
}

// ---------------- 3. dinv[i] = rsqrt(counts[i] + 1e-8), in place ----------------
__global__ void dinv_kernel(const int* __restrict__ counts, float* __restrict__ dinv) {
    int i = blockIdx.x * blockDim.x + threadIdx.x;
    if (i < N_TOTAL) {
        float d = (float)counts[i];
        dinv[i] = rsqrtf(d + 1e-8f);   // aliases counts: safe (read then write, same thread)
    }
}

// ---------------- 4. bucket-scatter edges into CSR col array ----------------
__global__ void bucket_kernel(const int* __restrict__ src,
                              const int* __restrict__ dst,
                              int* __restrict__ cursor,
                              int* __restrict__ col) {
    int e = blockIdx.x * blockDim.x + threadIdx.x;
    if (e < N_EDGES) {
        int s = src[e];
        int pos = atomicAdd(&cursor[s], 1);
        col[pos] = dst[e];
    }
}

// ------- 5. h = x = concat(user_w, item_w); out(acc) = x  (float4) -------
__global__ void init_kernel(const float4* __restrict__ user_w,
                            const float4* __restrict__ item_w,
                            float4* __restrict__ h,
                            float4* __restrict__ out) {
    int i = blockIdx.x * blockDim.x + threadIdx.x;
    const int n = N_TOTAL * (EMB_DIM / 4);
    if (i < n) {
        const int userN = N_USERS * (EMB_DIM / 4);
        float4 v = (i < userN) ? user_w[i] : item_w[i - userN];
        h[i] = v;
        out[i] = v;
    }
}

// ---------------- 6. gather SpMM + fused acc update ----------------
// One wave (64 lanes) per row; lane = dim. h_next[i] = sum_j w_ij h_prev[col_j];
// out[i] = (out[i] + h_next[i]) * scale.
__global__ __launch_bounds__(256) void gather_kernel(
        const int* __restrict__ offs,
        const int* __restrict__ col,
        const float* __restrict__ dinv,
        const float* __restrict__ h_prev,
        float* __restrict__ h_next,
        float* __restrict__ out,
        float scale) {
    int row = blockIdx.x * 4 + (threadIdx.x >> 6);
    int lane = threadIdx.x & 63;
    if (row >= N_TOTAL) return;
    int start = offs[row];
    int end = offs[row + 1];
    float wi = dinv[row];
    float acc = 0.0f;
    for (int j = start; j < end; ++j) {
        int c = col[j];
        float w = wi * dinv[c];
        acc += w * h_prev[(size_t)c * EMB_DIM + lane];
    }
    size_t idx = (size_t)row * EMB_DIM + lane;
    h_next[idx] = acc;
    out[idx] = (out[idx] + acc) * scale;
}

extern "C" void kernel_launch(void* const* d_in, const int* in_sizes, int n_in,
                              void* d_out, int out_size, void* d_ws, size_t ws_size,
                              hipStream_t stream) {
    const float* user_w = (const float*)d_in[0];
    const float* item_w = (const float*)d_in[1];
    const int*   src    = (const int*)d_in[2];
    const int*   dst    = (const int*)d_in[3];
    float* out = (float*)d_out;
    (void)in_sizes; (void)n_in; (void)out_size; (void)ws_size;

    // ---- workspace layout ----
    char* ws = (char*)d_ws;
    size_t off = 0;
    auto alloc = [&](size_t bytes) {
        char* p = ws + off;
        off = (off + bytes + 255) & ~(size_t)255;
        return p;
    };
    int*   counts    = (int*)  alloc((size_t)N_TOTAL * 4);        // later aliased as dinv
    int*   offs      = (int*)  alloc((size_t)(N_TOTAL + 1) * 4);
    int*   cursor    = (int*)  alloc((size_t)N_TOTAL * 4);
    int*   blocksums = (int*)  alloc((size_t)N_SCAN_BLOCKS * 4);
    int*   col       = (int*)  alloc((size_t)N_EDGES * 4);        // 16 MB
    float* h_a       = (float*)alloc((size_t)N_TOTAL * EMB_DIM * 4);  // 76.8 MB
    float* h_b       = (float*)alloc((size_t)N_TOTAL * EMB_DIM * 4);  // 76.8 MB
    float* dinv      = (float*)counts;

    const int B = 256;

    // 1. histogram
    hipMemsetAsync(counts, 0, (size_t)N_TOTAL * 4, stream);
    hist_kernel<<<(N_EDGES + B - 1) / B, B, 0, stream>>>(src, counts);
    // 2. scan -> offs, cursor
    scanA_kernel<<<N_SCAN_BLOCKS, B, 0, stream>>>(counts, offs, blocksums);
    scanB_kernel<<<1, 64, 0, stream>>>(blocksums, offs);
    scanC_kernel<<<(N_TOTAL + B - 1) / B, B, 0, stream>>>(offs, blocksums, cursor);
    // 3. dinv (in place over counts; runs after scanA consumed counts)
    dinv_kernel<<<(N_TOTAL + B - 1) / B, B, 0, stream>>>(counts, dinv);
    // 4. bucket scatter -> col
    bucket_kernel<<<(N_EDGES + B - 1) / B, B, 0, stream>>>(src, dst, cursor, col);
    // 5. init h0 and acc
    {
        int n = N_TOTAL * (EMB_DIM / 4);
        init_kernel<<<(n + B - 1) / B, B, 0, stream>>>(
            (const float4*)user_w, (const float4*)item_w,
            (float4*)h_a, (float4*)out);
    }
    // 6. three gather layers, acc fused
    float* h_prev = h_a;
    float* h_next = h_b;
    for (int l = 0; l < N_LAYERS; ++l) {
        float scale = (l == N_LAYERS - 1) ? (1.0f / (N_LAYERS + 1)) : 1.0f;
        gather_kernel<<<(N_TOTAL + 3) / 4, B, 0, stream>>>(
            offs, col, dinv, h_prev, h_next, out, scale);
        float* tmp = h_prev; h_prev = h_next; h_next = tmp;
    }
}

// Round 3
// 1280.470 us; speedup vs baseline: 8.2836x; 1.4260x over previous
//
#include <hip/hip_runtime.h>

#define N_USERS  200000
#define N_ITEMS  100000
#define N_TOTAL  300000
#define EMB_DIM  64
#define N_EDGES  4000000
#define N_LAYERS 3

#define SCAN_CHUNK 1024
#define N_SCAN_BLOCKS ((N_TOTAL + SCAN_CHUNK - 1) / SCAN_CHUNK)   // 293

// ---------------- 1. degree histogram (int): counts[src[e]]++ ----------------
__global__ void hist_kernel(const int* __restrict__ src, int* __restrict__ counts) {
    int e = blockIdx.x * blockDim.x + threadIdx.x;
    if (e < N_EDGES) atomicAdd(&counts[src[e]], 1);
}

// ---------------- 2a. per-block exclusive scan of counts -> offs ----------------
__global__ void scanA_kernel(const int* __restrict__ counts,
                             int* __restrict__ offs,
                             int* __restrict__ blocksums) {
    __shared__ int lds[256];
    int t = threadIdx.x, b = blockIdx.x;
    int base = b * SCAN_CHUNK + t * 4;
    int v[4];
#pragma unroll
    for (int k = 0; k < 4; ++k)
        v[k] = (base + k < N_TOTAL) ? counts[base + k] : 0;
    int s = v[0] + v[1] + v[2] + v[3];
    lds[t] = s;
    __syncthreads();
    for (int off = 1; off < 256; off <<= 1) {
        int x = (t >= off) ? lds[t - off] : 0;
        __syncthreads();
        lds[t] += x;
        __syncthreads();
    }
    int inc = lds[t];
    int exc = inc - s;
    if (t == 255) blocksums[b] = inc;
    int run = exc;
#pragma unroll
    for (int k = 0; k < 4; ++k) {
        if (base + k < N_TOTAL) offs[base + k] = run;
        run += v[k];
    }
}

// ---------------- 2b. parallel scan of the 293 block sums ----------------
__global__ void scanB_kernel(int* __restrict__ blocksums, int* __restrict__ offs) {
    __shared__ int lds[512];
    int t = threadIdx.x;
    int v = (t < N_SCAN_BLOCKS) ? blocksums[t] : 0;
    lds[t] = v;
    __syncthreads();
    for (int o = 1; o < 512; o <<= 1) {
        int x = (t >= o) ? lds[t - o] : 0;
        __syncthreads();
        lds[t] += x;
        __syncthreads();
    }
    if (t < N_SCAN_BLOCKS) blocksums[t] = lds[t] - v;   // exclusive
    if (t == N_SCAN_BLOCKS - 1) offs[N_TOTAL] = lds[t]; // == N_EDGES
}

// ------- 2c. add block offsets; cursor = offs -------
__global__ void scanC_kernel(int* __restrict__ offs,
                             const int* __restrict__ blocksums,
                             int* __restrict__ cursor) {
    int i = blockIdx.x * blockDim.x + threadIdx.x;
    if (i < N_TOTAL) {
        int o = offs[i] + blocksums[i >> 10];
        offs[i] = o;
        cursor[i] = o;
    }
}

// ---------------- 3. dinv[i] = rsqrt(counts[i] + 1e-8), in place ----------------
__global__ void dinv_kernel(const int* __restrict__ counts, float* __restrict__ dinv) {
    int i = blockIdx.x * blockDim.x + threadIdx.x;
    if (i < N_TOTAL) {
        float d = (float)counts[i];
        dinv[i] = rsqrtf(d + 1e-8f);
    }
}

// ---------------- 4. bucket-scatter edges into CSR col array ----------------
__global__ void bucket_kernel(const int* __restrict__ src,
                              const int* __restrict__ dst,
                              int* __restrict__ cursor,
                              int* __restrict__ col) {
    int e = blockIdx.x * blockDim.x + threadIdx.x;
    if (e < N_EDGES) {
        int s = src[e];
        int pos = atomicAdd(&cursor[s], 1);
        col[pos] = dst[e];
    }
}

// ---------------- 5. gather SpMM, edge-loop unrolled x4 ----------------
// MODE 0 (first): h_prev is concat(user_w,item_w) via predicated select;
//                 out = x + acc (no out read, no init kernel).
// MODE 1 (mid):   out += acc.
// MODE 2 (last):  out = (out + acc) / (N_LAYERS+1); h_next not written.
template <int MODE>
__device__ __forceinline__ float load_h(int c, int lane,
                                        const float* __restrict__ user_w,
                                        const float* __restrict__ item_w,
                                        const float* __restrict__ h_prev) {
    if (MODE == 0) {
        return (c < N_USERS) ? user_w[(size_t)c * EMB_DIM + lane]
                             : item_w[(size_t)(c - N_USERS) * EMB_DIM + lane];
    }
    return h_prev[(size_t)c * EMB_DIM + lane];
}

template <int MODE>
__global__ __launch_bounds__(256) void gather_kernel(
        const int* __restrict__ offs,
        const int* __restrict__ col,
        const float* __restrict__ dinv,
        const float* __restrict__ user_w,
        const float* __restrict__ item_w,
        const float* __restrict__ h_prev,
        float* __restrict__ h_next,
        float* __restrict__ out) {
    int row = blockIdx.x * 4 + (threadIdx.x >> 6);
    int lane = threadIdx.x & 63;
    if (row >= N_TOTAL) return;
    int start = offs[row];
    int end   = offs[row + 1];
    float wi = dinv[row];
    float a0 = 0.f, a1 = 0.f, a2 = 0.f, a3 = 0.f;
    int j = start;
    for (; j + 4 <= end; j += 4) {
        int c0 = col[j], c1 = col[j + 1], c2 = col[j + 2], c3 = col[j + 3];
        float w0 = wi * dinv[c0];
        float w1 = wi * dinv[c1];
        float w2 = wi * dinv[c2];
        float w3 = wi * dinv[c3];
        a0 += w0 * load_h<MODE>(c0, lane, user_w, item_w, h_prev);
        a1 += w1 * load_h<MODE>(c1, lane, user_w, item_w, h_prev);
        a2 += w2 * load_h<MODE>(c2, lane, user_w, item_w, h_prev);
        a3 += w3 * load_h<MODE>(c3, lane, user_w, item_w, h_prev);
    }
    for (; j < end; ++j) {
        int c = col[j];
        a0 += wi * dinv[c] * load_h<MODE>(c, lane, user_w, item_w, h_prev);
    }
    float acc = (a0 + a1) + (a2 + a3);
    size_t idx = (size_t)row * EMB_DIM + lane;
    if (MODE == 0) {
        float x = (row < N_USERS) ? user_w[idx]
                                  : item_w[idx - (size_t)N_USERS * EMB_DIM];
        h_next[idx] = acc;
        out[idx] = x + acc;
    } else if (MODE == 1) {
        h_next[idx] = acc;
        out[idx] += acc;
    } else {
        out[idx] = (out[idx] + acc) * (1.0f / (N_LAYERS + 1));
    }
}

extern "C" void kernel_launch(void* const* d_in, const int* in_sizes, int n_in,
                              void* d_out, int out_size, void* d_ws, size_t ws_size,
                              hipStream_t stream) {
    const float* user_w = (const float*)d_in[0];
    const float* item_w = (const float*)d_in[1];
    const int*   src    = (const int*)d_in[2];
    const int*   dst    = (const int*)d_in[3];
    float* out = (float*)d_out;
    (void)in_sizes; (void)n_in; (void)out_size; (void)ws_size;

    char* ws = (char*)d_ws;
    size_t off = 0;
    auto alloc = [&](size_t bytes) {
        char* p = ws + off;
        off = (off + bytes + 255) & ~(size_t)255;
        return p;
    };
    int*   counts    = (int*)  alloc((size_t)N_TOTAL * 4);        // aliased as dinv
    int*   offs      = (int*)  alloc((size_t)(N_TOTAL + 1) * 4);
    int*   cursor    = (int*)  alloc((size_t)N_TOTAL * 4);
    int*   blocksums = (int*)  alloc((size_t)N_SCAN_BLOCKS * 4);
    int*   col       = (int*)  alloc((size_t)N_EDGES * 4);        // 16 MB
    float* h_a       = (float*)alloc((size_t)N_TOTAL * EMB_DIM * 4);  // 76.8 MB
    float* h_b       = (float*)alloc((size_t)N_TOTAL * EMB_DIM * 4);  // 76.8 MB
    float* dinv      = (float*)counts;

    const int B = 256;
    const int gatherGrid = (N_TOTAL + 3) / 4;

    hipMemsetAsync(counts, 0, (size_t)N_TOTAL * 4, stream);
    hist_kernel<<<(N_EDGES + B - 1) / B, B, 0, stream>>>(src, counts);
    scanA_kernel<<<N_SCAN_BLOCKS, B, 0, stream>>>(counts, offs, blocksums);
    scanB_kernel<<<1, 512, 0, stream>>>(blocksums, offs);
    scanC_kernel<<<(N_TOTAL + B - 1) / B, B, 0, stream>>>(offs, blocksums, cursor);
    dinv_kernel<<<(N_TOTAL + B - 1) / B, B, 0, stream>>>(counts, dinv);
    bucket_kernel<<<(N_EDGES + B - 1) / B, B, 0, stream>>>(src, dst, cursor, col);

    // layer 1: x -> h_a, out = x + h_a
    gather_kernel<0><<<gatherGrid, B, 0, stream>>>(
        offs, col, dinv, user_w, item_w, nullptr, h_a, out);
    // layer 2: h_a -> h_b, out += h_b
    gather_kernel<1><<<gatherGrid, B, 0, stream>>>(
        offs, col, dinv, user_w, item_w, h_a, h_b, out);
    // layer 3: h_b -> (none), out = (out + acc)/4
    gather_kernel<2><<<gatherGrid, B, 0, stream>>>(
        offs, col, dinv, user_w, item_w, h_b, nullptr, out);
}

// Round 4
// 1271.133 us; speedup vs baseline: 8.3444x; 1.0073x over previous
//
#include <hip/hip_runtime.h>

#define N_USERS  200000
#define N_ITEMS  100000
#define N_TOTAL  300000
#define EMB_DIM  64
#define N_EDGES  4000000
#define N_LAYERS 3

#define SCAN_CHUNK 1024
#define N_SCAN_BLOCKS ((N_TOTAL + SCAN_CHUNK - 1) / SCAN_CHUNK)   // 293

#define BKT_BITS 7
#define BKT_ROWS (1 << BKT_BITS)                                   // 128 rows/bucket
#define NB ((N_TOTAL + BKT_ROWS - 1) >> BKT_BITS)                  // 2344 buckets

// ---- bf16 helpers: pack two fp32 -> uint (RNE), unpack uint -> two fp32 ----
__device__ __forceinline__ unsigned bfpack(float a, float b) {
    unsigned ua = __float_as_uint(a); ua = (ua + 0x7fffu + ((ua >> 16) & 1u)) >> 16;
    unsigned ub = __float_as_uint(b); ub = (ub + 0x7fffu + ((ub >> 16) & 1u)) >> 16;
    return ua | (ub << 16);
}
__device__ __forceinline__ float bflo(unsigned u) { return __uint_as_float(u << 16); }
__device__ __forceinline__ float bfhi(unsigned u) { return __uint_as_float(u & 0xffff0000u); }

// ---------------- 1. degree histogram (int): counts[src[e]]++ ----------------
__global__ void hist_kernel(const int* __restrict__ src, int* __restrict__ counts) {
    int e = blockIdx.x * blockDim.x + threadIdx.x;
    if (e < N_EDGES) atomicAdd(&counts[src[e]], 1);
}

// ---------------- 2a. per-block exclusive scan of counts -> offs ----------------
__global__ void scanA_kernel(const int* __restrict__ counts,
                             int* __restrict__ offs,
                             int* __restrict__ blocksums) {
    __shared__ int lds[256];
    int t = threadIdx.x, b = blockIdx.x;
    int base = b * SCAN_CHUNK + t * 4;
    int v[4];
#pragma unroll
    for (int k = 0; k < 4; ++k)
        v[k] = (base + k < N_TOTAL) ? counts[base + k] : 0;
    int s = v[0] + v[1] + v[2] + v[3];
    lds[t] = s;
    __syncthreads();
    for (int off = 1; off < 256; off <<= 1) {
        int x = (t >= off) ? lds[t - off] : 0;
        __syncthreads();
        lds[t] += x;
        __syncthreads();
    }
    int inc = lds[t];
    int exc = inc - s;
    if (t == 255) blocksums[b] = inc;
    int run = exc;
#pragma unroll
    for (int k = 0; k < 4; ++k) {
        if (base + k < N_TOTAL) offs[base + k] = run;
        run += v[k];
    }
}

// ---------------- 2b. parallel scan of the 293 block sums ----------------
__global__ void scanB_kernel(int* __restrict__ blocksums, int* __restrict__ offs) {
    __shared__ int lds[512];
    int t = threadIdx.x;
    int v = (t < N_SCAN_BLOCKS) ? blocksums[t] : 0;
    lds[t] = v;
    __syncthreads();
    for (int o = 1; o < 512; o <<= 1) {
        int x = (t >= o) ? lds[t - o] : 0;
        __syncthreads();
        lds[t] += x;
        __syncthreads();
    }
    if (t < N_SCAN_BLOCKS) blocksums[t] = lds[t] - v;   // exclusive
    if (t == N_SCAN_BLOCKS - 1) offs[N_TOTAL] = lds[t]; // == N_EDGES
}

// ------- 2c. add block offsets -------
__global__ void scanC_kernel(int* __restrict__ offs,
                             const int* __restrict__ blocksums) {
    int i = blockIdx.x * blockDim.x + threadIdx.x;
    if (i < N_TOTAL) offs[i] += blocksums[i >> 10];
}

// ---------------- 3. dinv[i] = rsqrt(counts[i] + 1e-8), in place ----------------
__global__ void dinv_kernel(const int* __restrict__ counts, float* __restrict__ dinv) {
    int i = blockIdx.x * blockDim.x + threadIdx.x;
    if (i < N_TOTAL) {
        float d = (float)counts[i];
        dinv[i] = rsqrtf(d + 1e-8f);
    }
}

// ---------------- 4a. bucket cursor init: bcursor[b] = offs[b<<BKT_BITS] ----------------
__global__ void bcur_kernel(const int* __restrict__ offs, int* __restrict__ bcursor) {
    int b = blockIdx.x * blockDim.x + threadIdx.x;
    if (b < NB) bcursor[b] = offs[b << BKT_BITS];
}

// ---- 4b. pass 1: partition edges into CSR-aligned, src-range buckets ----
// Write frontier = NB (~2344) cache lines -> minimal write amplification.
__global__ void part1_kernel(const int* __restrict__ src,
                             const int* __restrict__ dst,
                             int* __restrict__ bcursor,
                             int2* __restrict__ edgebuf) {
    int e = blockIdx.x * blockDim.x + threadIdx.x;
    if (e < N_EDGES) {
        int s = src[e];
        int d = dst[e];
        int pos = atomicAdd(&bcursor[s >> BKT_BITS], 1);
        edgebuf[pos] = make_int2(s, d);
    }
}

// ---- 4c. pass 2: within each bucket, scatter to exact CSR position ----
// One block per bucket; LDS row cursors; col writes land in the bucket's
// contiguous ~7 KB window (L2-resident, no HBM write thrash).
__global__ __launch_bounds__(256) void part2_kernel(const int* __restrict__ offs,
                                                    const int2* __restrict__ edgebuf,
                                                    int* __restrict__ col) {
    __shared__ int lcur[BKT_ROWS];
    int b = blockIdx.x;
    int base = b << BKT_BITS;
    int nrows = N_TOTAL - base; if (nrows > BKT_ROWS) nrows = BKT_ROWS;
    int t = threadIdx.x;
    if (t < nrows) lcur[t] = offs[base + t];
    __syncthreads();
    int estart = offs[base];
    int eend   = offs[base + nrows];
    for (int j = estart + t; j < eend; j += 256) {
        int2 ed = edgebuf[j];
        int pos = atomicAdd(&lcur[ed.x - base], 1);
        col[pos] = ed.y;
    }
}

// ---------------- 5. convert x = concat(user_w,item_w) to bf16 ----------------
__global__ void convert_kernel(const float4* __restrict__ user_w,
                               const float4* __restrict__ item_w,
                               uint2* __restrict__ xbf) {
    int i = blockIdx.x * blockDim.x + threadIdx.x;   // over N_TOTAL*16 float4s
    const int n = N_TOTAL * (EMB_DIM / 4);
    if (i < n) {
        const int userN = N_USERS * (EMB_DIM / 4);
        float4 v = (i < userN) ? user_w[i] : item_w[i - userN];
        xbf[i] = make_uint2(bfpack(v.x, v.y), bfpack(v.z, v.w));
    }
}

// ---------------- 6. gather SpMM, bf16 rows, 2 edges per wave ----------------
// wave = 1 row; half-wave (32 lanes) = 1 edge; lane m handles dims 2m,2m+1.
// MODE 0: out = x + acc, write hnext.  MODE 1: out += acc, write hnext.
// MODE 2: out = (out + acc)/4, no hnext.
template <int MODE>
__global__ __launch_bounds__(256) void gather_kernel(
        const int* __restrict__ offs,
        const int* __restrict__ col,
        const float* __restrict__ dinv,
        const unsigned* __restrict__ hprev,   // bf16x2, 32 uints per row
        unsigned* __restrict__ hnext,
        float2* __restrict__ out2,
        const float2* __restrict__ uw2,
        const float2* __restrict__ iw2) {
    int row  = blockIdx.x * 4 + (threadIdx.x >> 6);
    int lane = threadIdx.x & 63;
    int sub  = lane >> 5;        // which edge of the pair
    int m    = lane & 31;        // dim pair index
    int start = offs[row];
    int end   = offs[row + 1];
    float wi = dinv[row];
    float a0 = 0.f, a1 = 0.f;
    int j = start + sub;
    for (; j + 2 < end; j += 4) {           // 2 edges per half-wave in flight
        int c0 = col[j];
        int c1 = col[j + 2];
        float w0 = wi * dinv[c0];
        float w1 = wi * dinv[c1];
        unsigned u0 = hprev[c0 * 32 + m];
        unsigned u1 = hprev[c1 * 32 + m];
        a0 = fmaf(w0, bflo(u0), a0);
        a1 = fmaf(w0, bfhi(u0), a1);
        a0 = fmaf(w1, bflo(u1), a0);
        a1 = fmaf(w1, bfhi(u1), a1);
    }
    for (; j < end; j += 2) {
        int c = col[j];
        float w = wi * dinv[c];
        unsigned u = hprev[c * 32 + m];
        a0 = fmaf(w, bflo(u), a0);
        a1 = fmaf(w, bfhi(u), a1);
    }
    // combine the two half-wave partial sums (same dims in both halves)
    a0 += __shfl_xor(a0, 32);
    a1 += __shfl_xor(a1, 32);
    if (sub == 0) {
        int p = row * 32 + m;
        if (MODE == 0) {
            float2 x = (row < N_USERS) ? uw2[p] : iw2[p - N_USERS * 32];
            hnext[p] = bfpack(a0, a1);
            out2[p] = make_float2(x.x + a0, x.y + a1);
        } else if (MODE == 1) {
            float2 o = out2[p];
            hnext[p] = bfpack(a0, a1);
            out2[p] = make_float2(o.x + a0, o.y + a1);
        } else {
            float2 o = out2[p];
            out2[p] = make_float2((o.x + a0) * 0.25f, (o.y + a1) * 0.25f);
        }
    }
}

extern "C" void kernel_launch(void* const* d_in, const int* in_sizes, int n_in,
                              void* d_out, int out_size, void* d_ws, size_t ws_size,
                              hipStream_t stream) {
    const float* user_w = (const float*)d_in[0];
    const float* item_w = (const float*)d_in[1];
    const int*   src    = (const int*)d_in[2];
    const int*   dst    = (const int*)d_in[3];
    float* out = (float*)d_out;
    (void)in_sizes; (void)n_in; (void)out_size; (void)ws_size;

    char* ws = (char*)d_ws;
    size_t off = 0;
    auto alloc = [&](size_t bytes) {
        char* p = ws + off;
        off = (off + bytes + 255) & ~(size_t)255;
        return p;
    };
    int*      counts    = (int*)     alloc((size_t)N_TOTAL * 4);       // aliased as dinv
    int*      offs      = (int*)     alloc((size_t)(N_TOTAL + 1) * 4);
    int*      blocksums = (int*)     alloc((size_t)N_SCAN_BLOCKS * 4);
    int*      bcursor   = (int*)     alloc((size_t)NB * 4);
    int*      col       = (int*)     alloc((size_t)N_EDGES * 4);       // 16 MB
    int2*     edgebuf   = (int2*)    alloc((size_t)N_EDGES * 8);       // 32 MB
    unsigned* xbf       = (unsigned*)alloc((size_t)N_TOTAL * 32 * 4);  // 38.4 MB
    unsigned* hbf_a     = (unsigned*)alloc((size_t)N_TOTAL * 32 * 4);  // 38.4 MB
    unsigned* hbf_b     = (unsigned*)alloc((size_t)N_TOTAL * 32 * 4);  // 38.4 MB
    float*    dinv      = (float*)counts;

    const int B = 256;
    const int gatherGrid = N_TOTAL / 4;   // 75000, exact

    hipMemsetAsync(counts, 0, (size_t)N_TOTAL * 4, stream);
    hist_kernel<<<(N_EDGES + B - 1) / B, B, 0, stream>>>(src, counts);
    scanA_kernel<<<N_SCAN_BLOCKS, B, 0, stream>>>(counts, offs, blocksums);
    scanB_kernel<<<1, 512, 0, stream>>>(blocksums, offs);
    scanC_kernel<<<(N_TOTAL + B - 1) / B, B, 0, stream>>>(offs, blocksums);
    dinv_kernel<<<(N_TOTAL + B - 1) / B, B, 0, stream>>>(counts, dinv);
    bcur_kernel<<<(NB + B - 1) / B, B, 0, stream>>>(offs, bcursor);
    part1_kernel<<<(N_EDGES + B - 1) / B, B, 0, stream>>>(src, dst, bcursor, edgebuf);
    part2_kernel<<<NB, B, 0, stream>>>(offs, edgebuf, col);
    convert_kernel<<<(N_TOTAL * 16 + B - 1) / B, B, 0, stream>>>(
        (const float4*)user_w, (const float4*)item_w, (uint2*)xbf);

    const float2* uw2 = (const float2*)user_w;
    const float2* iw2 = (const float2*)item_w;
    float2* out2 = (float2*)out;
    // layer 1: xbf -> hbf_a, out = x + acc
    gather_kernel<0><<<gatherGrid, B, 0, stream>>>(
        offs, col, dinv, xbf, hbf_a, out2, uw2, iw2);
    // layer 2: hbf_a -> hbf_b, out += acc
    gather_kernel<1><<<gatherGrid, B, 0, stream>>>(
        offs, col, dinv, hbf_a, hbf_b, out2, uw2, iw2);
    // layer 3: hbf_b -> (none), out = (out + acc)/4
    gather_kernel<2><<<gatherGrid, B, 0, stream>>>(
        offs, col, dinv, hbf_b, nullptr, out2, uw2, iw2);
}

// Round 5
// 879.677 us; speedup vs baseline: 12.0577x; 1.4450x over previous
//
#include <hip/hip_runtime.h>

#define N_USERS  200000
#define N_ITEMS  100000
#define N_TOTAL  300000
#define EMB_DIM  64
#define N_EDGES  4000000
#define N_LAYERS 3

// generic scan: 1024 elements per scan block
#define SCAN_CHUNK 1024
#define NSB_OFFS ((N_TOTAL + SCAN_CHUNK - 1) / SCAN_CHUNK)        // 293

// radix partition: 512-row buckets, 8192-edge chunks
#define B2_BITS 9
#define B2_ROWS (1 << B2_BITS)                                     // 512
#define NB2 ((N_TOTAL + B2_ROWS - 1) >> B2_BITS)                   // 586
#define CHUNK_E 8192
#define NBLK ((N_EDGES + CHUNK_E - 1) / CHUNK_E)                   // 489
#define NFLAT (NB2 * NBLK)                                         // 286,554
#define NSB_FLAT ((NFLAT + SCAN_CHUNK - 1) / SCAN_CHUNK)           // 280

// ---- bf16 helpers ----
__device__ __forceinline__ unsigned bfpack(float a, float b) {
    unsigned ua = __float_as_uint(a); ua = (ua + 0x7fffu + ((ua >> 16) & 1u)) >> 16;
    unsigned ub = __float_as_uint(b); ub = (ub + 0x7fffu + ((ub >> 16) & 1u)) >> 16;
    return ua | (ub << 16);
}
__device__ __forceinline__ float bflo(unsigned u) { return __uint_as_float(u << 16); }
__device__ __forceinline__ float bfhi(unsigned u) { return __uint_as_float(u & 0xffff0000u); }

// ---------------- 1. degree histogram ----------------
__global__ void hist_kernel(const int* __restrict__ src, int* __restrict__ counts) {
    int e = blockIdx.x * blockDim.x + threadIdx.x;
    if (e < N_EDGES) atomicAdd(&counts[src[e]], 1);
}

// ---------------- generic 3-pass exclusive scan ----------------
__global__ void scanA_g(const int* __restrict__ in, int* __restrict__ out,
                        int* __restrict__ bsums, int n) {
    __shared__ int lds[256];
    int t = threadIdx.x, b = blockIdx.x;
    int base = b * SCAN_CHUNK + t * 4;
    int v[4];
#pragma unroll
    for (int k = 0; k < 4; ++k)
        v[k] = (base + k < n) ? in[base + k] : 0;
    int s = v[0] + v[1] + v[2] + v[3];
    lds[t] = s;
    __syncthreads();
    for (int off = 1; off < 256; off <<= 1) {
        int x = (t >= off) ? lds[t - off] : 0;
        __syncthreads();
        lds[t] += x;
        __syncthreads();
    }
    int inc = lds[t];
    int exc = inc - s;
    if (t == 255) bsums[b] = inc;
    int run = exc;
#pragma unroll
    for (int k = 0; k < 4; ++k) {
        if (base + k < n) out[base + k] = run;
        run += v[k];
    }
}

__global__ void scanB_g(int* __restrict__ bsums, int nb, int* __restrict__ total_out) {
    __shared__ int lds[512];
    int t = threadIdx.x;
    int v = (t < nb) ? bsums[t] : 0;
    lds[t] = v;
    __syncthreads();
    for (int o = 1; o < 512; o <<= 1) {
        int x = (t >= o) ? lds[t - o] : 0;
        __syncthreads();
        lds[t] += x;
        __syncthreads();
    }
    if (t < nb) bsums[t] = lds[t] - v;       // exclusive
    if (total_out && t == nb - 1) *total_out = lds[t];
}

__global__ void scanC_g(int* __restrict__ out, const int* __restrict__ bsums, int n) {
    int i = blockIdx.x * blockDim.x + threadIdx.x;
    if (i < n) out[i] += bsums[i >> 10];
}

// ---------------- dinv = rsqrt(counts + 1e-8), in place ----------------
__global__ void dinv_kernel(const int* __restrict__ counts, float* __restrict__ dinv) {
    int i = blockIdx.x * blockDim.x + threadIdx.x;
    if (i < N_TOTAL) {
        float d = (float)counts[i];
        dinv[i] = rsqrtf(d + 1e-8f);
    }
}

// ---- partition phase A: per-(block,bucket) counts via LDS ----
__global__ __launch_bounds__(256) void partA_kernel(const int* __restrict__ src,
                                                    int* __restrict__ bcnt) {
    __shared__ int lcnt[NB2];
    int blk = blockIdx.x, t = threadIdx.x;
    for (int i = t; i < NB2; i += 256) lcnt[i] = 0;
    __syncthreads();
    int base = blk * CHUNK_E;
    int end = base + CHUNK_E; if (end > N_EDGES) end = N_EDGES;
    for (int e = base + t; e < end; e += 256)
        atomicAdd(&lcnt[src[e] >> B2_BITS], 1);
    __syncthreads();
    for (int i = t; i < NB2; i += 256)
        bcnt[(size_t)i * NBLK + blk] = lcnt[i];
}

// ---- partition phase C: write edges into block-private ranges ----
__global__ __launch_bounds__(256) void partC_kernel(const int* __restrict__ src,
                                                    const int* __restrict__ dst,
                                                    const int* __restrict__ boffs,
                                                    int2* __restrict__ edgebuf) {
    __shared__ int lcur[NB2];
    int blk = blockIdx.x, t = threadIdx.x;
    for (int i = t; i < NB2; i += 256) lcur[i] = boffs[(size_t)i * NBLK + blk];
    __syncthreads();
    int base = blk * CHUNK_E;
    int end = base + CHUNK_E; if (end > N_EDGES) end = N_EDGES;
    for (int e = base + t; e < end; e += 256) {
        int s = src[e], d = dst[e];
        int pos = atomicAdd(&lcur[s >> B2_BITS], 1);
        edgebuf[pos] = make_int2(s, d);
    }
}

// ---- final fine scatter: one block per 512-row bucket, block-local window ----
__global__ __launch_bounds__(256) void part2_kernel(const int* __restrict__ offs,
                                                    const int2* __restrict__ edgebuf,
                                                    int* __restrict__ col) {
    __shared__ int lcur[B2_ROWS];
    int b = blockIdx.x;
    int base = b << B2_BITS;
    int nrows = N_TOTAL - base; if (nrows > B2_ROWS) nrows = B2_ROWS;
    int t = threadIdx.x;
    for (int i = t; i < nrows; i += 256) lcur[i] = offs[base + i];
    __syncthreads();
    int estart = offs[base];
    int eend   = offs[base + nrows];
    for (int j = estart + t; j < eend; j += 256) {
        int2 ed = edgebuf[j];
        int pos = atomicAdd(&lcur[ed.x - base], 1);
        col[pos] = ed.y;
    }
}

// ---- g0 = dinv ⊙ concat(user_w, item_w), bf16x2 packed ----
__global__ void convert_kernel(const float2* __restrict__ uw2,
                               const float2* __restrict__ iw2,
                               const float* __restrict__ dinv,
                               unsigned* __restrict__ g0) {
    int i = blockIdx.x * blockDim.x + threadIdx.x;    // N_TOTAL*32 uints
    const int n = N_TOTAL * 32;
    if (i < n) {
        int row = i >> 5;
        float2 x = (row < N_USERS) ? uw2[i] : iw2[i - N_USERS * 32];
        float di = dinv[row];
        g0[i] = bfpack(di * x.x, di * x.y);
    }
}

// ---------------- gather SpMM on pre-scaled g tables ----------------
// h_next[row] = dinv[row] * sum_{edges} g_prev[col];  g_next = dinv * h_next.
// wave = row; half-wave = edge stream; lane m handles dims 2m,2m+1.
// MODE 0: out = x + h.  MODE 1: out += h.  MODE 2: out = (out+h)/4, no g_next.
template <int MODE>
__global__ __launch_bounds__(256) void gather_kernel(
        const int* __restrict__ offs,
        const int* __restrict__ col,
        const float* __restrict__ dinv,
        const unsigned* __restrict__ gprev,
        unsigned* __restrict__ gnext,
        float2* __restrict__ out2,
        const float2* __restrict__ uw2,
        const float2* __restrict__ iw2) {
    int row  = blockIdx.x * 4 + (threadIdx.x >> 6);
    int lane = threadIdx.x & 63;
    int sub  = lane >> 5;
    int m    = lane & 31;
    int start = offs[row];
    int end   = offs[row + 1];
    float a0 = 0.f, a1 = 0.f;
    int j = start + sub;
    for (; j + 6 < end; j += 8) {             // 4 edges in flight per half-wave
        int c0 = col[j], c1 = col[j + 2], c2 = col[j + 4], c3 = col[j + 6];
        unsigned u0 = gprev[c0 * 32 + m];
        unsigned u1 = gprev[c1 * 32 + m];
        unsigned u2 = gprev[c2 * 32 + m];
        unsigned u3 = gprev[c3 * 32 + m];
        a0 += bflo(u0); a1 += bfhi(u0);
        a0 += bflo(u1); a1 += bfhi(u1);
        a0 += bflo(u2); a1 += bfhi(u2);
        a0 += bflo(u3); a1 += bfhi(u3);
    }
    for (; j < end; j += 2) {
        unsigned u = gprev[col[j] * 32 + m];
        a0 += bflo(u); a1 += bfhi(u);
    }
    a0 += __shfl_xor(a0, 32);
    a1 += __shfl_xor(a1, 32);
    if (sub == 0) {
        float di = dinv[row];
        float h0 = di * a0, h1 = di * a1;
        int p = row * 32 + m;
        if (MODE == 0) {
            float2 x = (row < N_USERS) ? uw2[p] : iw2[p - N_USERS * 32];
            gnext[p] = bfpack(di * h0, di * h1);
            out2[p] = make_float2(x.x + h0, x.y + h1);
        } else if (MODE == 1) {
            float2 o = out2[p];
            gnext[p] = bfpack(di * h0, di * h1);
            out2[p] = make_float2(o.x + h0, o.y + h1);
        } else {
            float2 o = out2[p];
            out2[p] = make_float2((o.x + h0) * 0.25f, (o.y + h1) * 0.25f);
        }
    }
}

extern "C" void kernel_launch(void* const* d_in, const int* in_sizes, int n_in,
                              void* d_out, int out_size, void* d_ws, size_t ws_size,
                              hipStream_t stream) {
    const float* user_w = (const float*)d_in[0];
    const float* item_w = (const float*)d_in[1];
    const int*   src    = (const int*)d_in[2];
    const int*   dst    = (const int*)d_in[3];
    float* out = (float*)d_out;
    (void)in_sizes; (void)n_in; (void)out_size; (void)ws_size;

    char* ws = (char*)d_ws;
    size_t off = 0;
    auto alloc = [&](size_t bytes) {
        char* p = ws + off;
        off = (off + bytes + 255) & ~(size_t)255;
        return p;
    };
    int*      counts = (int*)     alloc((size_t)N_TOTAL * 4);        // aliased dinv
    int*      offs   = (int*)     alloc((size_t)(N_TOTAL + 1) * 4);
    int*      bs1    = (int*)     alloc((size_t)NSB_OFFS * 4);
    int*      bcnt   = (int*)     alloc((size_t)NFLAT * 4);          // 1.15 MB
    int*      boffs  = (int*)     alloc((size_t)NFLAT * 4);          // 1.15 MB
    int*      bs2    = (int*)     alloc((size_t)NSB_FLAT * 4);
    int*      col    = (int*)     alloc((size_t)N_EDGES * 4);        // 16 MB
    int2*     edgebuf= (int2*)    alloc((size_t)N_EDGES * 8);        // 32 MB
    unsigned* g0     = (unsigned*)alloc((size_t)N_TOTAL * 32 * 4);   // 38.4 MB
    unsigned* g_a    = (unsigned*)alloc((size_t)N_TOTAL * 32 * 4);   // 38.4 MB
    unsigned* g_b    = (unsigned*)alloc((size_t)N_TOTAL * 32 * 4);   // 38.4 MB
    float*    dinv   = (float*)counts;

    const int B = 256;
    const int gatherGrid = N_TOTAL / 4;   // 75000

    // degree + row offsets
    hipMemsetAsync(counts, 0, (size_t)N_TOTAL * 4, stream);
    hist_kernel<<<(N_EDGES + B - 1) / B, B, 0, stream>>>(src, counts);
    scanA_g<<<NSB_OFFS, B, 0, stream>>>(counts, offs, bs1, N_TOTAL);
    scanB_g<<<1, 512, 0, stream>>>(bs1, NSB_OFFS, &offs[N_TOTAL]);
    scanC_g<<<(N_TOTAL + B - 1) / B, B, 0, stream>>>(offs, bs1, N_TOTAL);
    dinv_kernel<<<(N_TOTAL + B - 1) / B, B, 0, stream>>>(counts, dinv);

    // radix partition into 512-row buckets (block-private write ranges)
    partA_kernel<<<NBLK, B, 0, stream>>>(src, bcnt);
    scanA_g<<<NSB_FLAT, B, 0, stream>>>(bcnt, boffs, bs2, NFLAT);
    scanB_g<<<1, 512, 0, stream>>>(bs2, NSB_FLAT, nullptr);
    scanC_g<<<(NFLAT + B - 1) / B, B, 0, stream>>>(boffs, bs2, NFLAT);
    partC_kernel<<<NBLK, B, 0, stream>>>(src, dst, boffs, edgebuf);
    part2_kernel<<<NB2, B, 0, stream>>>(offs, edgebuf, col);

    // g0 = dinv * x (bf16)
    convert_kernel<<<(N_TOTAL * 32 + B - 1) / B, B, 0, stream>>>(
        (const float2*)user_w, (const float2*)item_w, dinv, g0);

    const float2* uw2 = (const float2*)user_w;
    const float2* iw2 = (const float2*)item_w;
    float2* out2 = (float2*)out;
    gather_kernel<0><<<gatherGrid, B, 0, stream>>>(offs, col, dinv, g0,  g_a, out2, uw2, iw2);
    gather_kernel<1><<<gatherGrid, B, 0, stream>>>(offs, col, dinv, g_a, g_b, out2, uw2, iw2);
    gather_kernel<2><<<gatherGrid, B, 0, stream>>>(offs, col, dinv, g_b, nullptr, out2, uw2, iw2);
}